// Round 5
// baseline (295.103 us; speedup 1.0000x reference)
//
#include <hip/hip_runtime.h>
#include <math.h>

#define VOL    (128*128*128)
#define PLANE  (128*128)
#define PLANE4 (PLANE/4)      // 4096 float4 per plane
#define SQ_BLOCKS 1024

// ---------------- reduction helpers ----------------

__device__ __forceinline__ double wave_reduce_d(double v) {
    #pragma unroll
    for (int off = 32; off > 0; off >>= 1)
        v += __shfl_down(v, off, 64);
    return v;
}

__device__ __forceinline__ void block_reduce1_atomic(double a, double* dst) {
    __shared__ double s1[4];
    int lane = threadIdx.x & 63;
    int wave = threadIdx.x >> 6;
    a = wave_reduce_d(a);
    if (lane == 0) s1[wave] = a;
    __syncthreads();
    if (threadIdx.x == 0)
        atomicAdd(&dst[0], s1[0] + s1[1] + s1[2] + s1[3]);
}

__device__ __forceinline__ void block_reduce2_atomic(double a, double b, double* dst) {
    __shared__ double s2[2][4];
    int lane = threadIdx.x & 63;
    int wave = threadIdx.x >> 6;
    a = wave_reduce_d(a);
    b = wave_reduce_d(b);
    if (lane == 0) { s2[0][wave] = a; s2[1][wave] = b; }
    __syncthreads();
    if (threadIdx.x == 0) {
        atomicAdd(&dst[0], s2[0][0] + s2[0][1] + s2[0][2] + s2[0][3]);
        atomicAdd(&dst[1], s2[1][0] + s2[1][1] + s2[1][2] + s2[1][3]);
    }
}

__device__ __forceinline__ void block_reduce3_atomic(double a, double b, double c, double* dst) {
    __shared__ double s3[3][4];
    int lane = threadIdx.x & 63;
    int wave = threadIdx.x >> 6;
    a = wave_reduce_d(a);
    b = wave_reduce_d(b);
    c = wave_reduce_d(c);
    if (lane == 0) { s3[0][wave] = a; s3[1][wave] = b; s3[2][wave] = c; }
    __syncthreads();
    if (threadIdx.x == 0) {
        atomicAdd(&dst[0], s3[0][0] + s3[0][1] + s3[0][2] + s3[0][3]);
        atomicAdd(&dst[1], s3[1][0] + s3[1][1] + s3[1][2] + s3[1][3]);
        atomicAdd(&dst[2], s3[2][0] + s3[2][1] + s3[2][2] + s3[2][3]);
    }
}

// ws doubles layout:
// [0] sum((F_0g-F_0)^2) | [1..3] lcc0 | [4..6] lcc1 | [7..8] tv0 | [9..10] tv1
// Bz float buffer starts at byte offset 256: 8 volumes x VOL floats.

__global__ void zero_ws_kernel(double* ws) {
    if (threadIdx.x < 16) ws[threadIdx.x] = 0.0;
}

__device__ __forceinline__ float4 f4z() { return make_float4(0.f, 0.f, 0.f, 0.f); }

// x-box-sum of a full 128-row held as float4-per-lane across a 32-lane segment.
// Lane quad q holds x = 4q..4q+3; zero padding at row ends. (R4-verified.)
__device__ __forceinline__ float4 xbox(float4 b, int q) {
    float lz = __shfl_up(b.z, 1, 32);
    float lw = __shfl_up(b.w, 1, 32);
    float rx = __shfl_down(b.x, 1, 32);
    float ry = __shfl_down(b.y, 1, 32);
    if (q == 0)  { lz = 0.0f; lw = 0.0f; }
    if (q == 31) { rx = 0.0f; ry = 0.0f; }
    float s = b.x + b.y + b.z + b.w;
    float4 o;
    o.x = lz + lw + (s - b.w);
    o.y = lw + s;
    o.z = s + rx;
    o.w = (s - b.x) + rx + ry;
    return o;
}

// ---------------- dispatch 2: z-pass (8 vols) + sqdiff ----------------
// blocks: 1536. b%3==0 -> zpass id=b/3 in [0,512); else sqdiff id=(b/3)*2+(b%3-1).
// zpass block: one volume, z-chunk of 32 (+4 halo), 8 y-rows x 32 x-quads.

__global__ __launch_bounds__(256) void k_zpass_sq(
    const float* __restrict__ F0,  const float* __restrict__ F0g,
    const float* __restrict__ I0,  const float* __restrict__ I0R,
    const float* __restrict__ I1,  const float* __restrict__ I1R,
    double* __restrict__ ws, float* __restrict__ bz)
{
    int b = blockIdx.x;
    int tid = threadIdx.x;
    int r = b % 3;
    int q3 = b / 3;

    if (r == 0) {
        int id = q3;                        // [0,512)
        int yg = id & 15;
        int zc = (id >> 4) & 3;
        int v  = id >> 6;                   // [0,8)
        int a  = v >> 1, batch = v & 1;
        const float* src = (a == 0) ? I0 : (a == 1) ? I0R : (a == 2) ? I1 : I1R;
        const float4* V = (const float4*)(src + (size_t)batch * VOL);
        float4* BZ = (float4*)bz + (size_t)v * (VOL / 4);

        int xq = tid & 31, yl = tid >> 5;
        int pidx = (yg * 8 + yl) * 32 + xq;
        int z0 = zc << 5;

        float4 r0 = f4z(), r1 = f4z(), r2 = f4z(), r3 = f4z(), r4 = f4z();
        #pragma unroll
        for (int s = 0; s < 36; ++s) {
            int z = z0 - 2 + s;
            int zcl = z < 0 ? 0 : (z > 127 ? 127 : z);
            float4 t = V[(size_t)zcl * PLANE4 + pidx];
            if (z < 0 || z > 127) t = f4z();
            r0 = r1; r1 = r2; r2 = r3; r3 = r4; r4 = t;
            if (s >= 4) {
                float4 sm;
                sm.x = r0.x + r1.x + r2.x + r3.x + r4.x;
                sm.y = r0.y + r1.y + r2.y + r3.y + r4.y;
                sm.z = r0.z + r1.z + r2.z + r3.z + r4.z;
                sm.w = r0.w + r1.w + r2.w + r3.w + r4.w;
                BZ[(size_t)(z - 2) * PLANE4 + pidx] = sm;
            }
        }
    } else {
        // sqdiff: 3,145,728 float4, exactly 12/thread
        int bid = q3 * 2 + (r - 1);         // [0,1024)
        const float4* A = (const float4*)F0;
        const float4* B = (const float4*)F0g;
        int idx = bid * 256 + tid;
        const int stride = SQ_BLOCKS * 256;
        float acc = 0.f;
        #pragma unroll
        for (int k = 0; k < 12; ++k) {
            int i = idx + k * stride;
            float4 xx = A[i], yy = B[i];
            float d0 = yy.x - xx.x, d1 = yy.y - xx.y;
            float d2 = yy.z - xx.z, d3 = yy.w - xx.w;
            acc += (d0 * d0 + d1 * d1) + (d2 * d2 + d3 * d3);
        }
        block_reduce1_atomic((double)acc, &ws[0]);
    }
}

// ---------------- dispatch 3: y/x-pass + reduce (LCC) + tversky ----------------
// blocks: 1024. even -> lcc id=b>>1 in [0,512); odd -> tversky id=b>>1 in [0,512).
// lcc block: one (pair,batch), y-chunk of 16 (+4 halo), 8 z x 32 x-quads.

__global__ __launch_bounds__(256) void k_lcc_tv(
    const float* __restrict__ I0,  const float* __restrict__ I0R,
    const float* __restrict__ I1,  const float* __restrict__ I1R,
    const float* __restrict__ S0,  const float* __restrict__ S0g,
    const float* __restrict__ S1,  const float* __restrict__ S1g,
    double* __restrict__ ws, const float* __restrict__ bz)
{
    int b = blockIdx.x;
    int tid = threadIdx.x;

    if ((b & 1) == 0) {
        int id = b >> 1;                    // [0,512)
        int zg = id & 15;
        int yc = (id >> 4) & 7;
        int batch = (id >> 7) & 1;
        int pair = id >> 8;

        const float* gsrc = pair ? I1  : I0;
        const float* psrc = pair ? I1R : I0R;
        const float4* G = (const float4*)(gsrc + (size_t)batch * VOL);
        const float4* P = (const float4*)(psrc + (size_t)batch * VOL);
        const float4* BG = (const float4*)bz + (size_t)(4 * pair + batch)     * (VOL / 4);
        const float4* BP = (const float4*)bz + (size_t)(4 * pair + 2 + batch) * (VOL / 4);
        double* dst = ws + (pair ? 4 : 1);

        int xq = tid & 31, zl = tid >> 5;
        int z = zg * 8 + zl;
        int y0 = yc << 4;
        size_t zb = (size_t)z * PLANE4;

        float4 g0 = f4z(), g1 = f4z(), g2 = f4z(), g3 = f4z(), g4 = f4z();
        float4 p0 = f4z(), p1 = f4z(), p2 = f4z(), p3 = f4z(), p4 = f4z();
        float a1 = 0.f, a2 = 0.f, a3 = 0.f;
        const float inv = 1.0f / 125.0f;

        #pragma unroll
        for (int s = 0; s < 20; ++s) {
            int y = y0 - 2 + s;
            int ycl = y < 0 ? 0 : (y > 127 ? 127 : y);
            size_t ri = zb + (size_t)ycl * 32 + xq;
            float4 tg = BG[ri];
            float4 tp = BP[ri];
            if (y < 0 || y > 127) { tg = f4z(); tp = f4z(); }
            g0 = g1; g1 = g2; g2 = g3; g3 = g4; g4 = tg;
            p0 = p1; p1 = p2; p2 = p3; p3 = p4; p4 = tp;
            if (s >= 4) {
                int yo = y0 + s - 4;
                float4 sg, sp;
                sg.x = g0.x + g1.x + g2.x + g3.x + g4.x;
                sg.y = g0.y + g1.y + g2.y + g3.y + g4.y;
                sg.z = g0.z + g1.z + g2.z + g3.z + g4.z;
                sg.w = g0.w + g1.w + g2.w + g3.w + g4.w;
                sp.x = p0.x + p1.x + p2.x + p3.x + p4.x;
                sp.y = p0.y + p1.y + p2.y + p3.y + p4.y;
                sp.z = p0.z + p1.z + p2.z + p3.z + p4.z;
                sp.w = p0.w + p1.w + p2.w + p3.w + p4.w;
                float4 bg3 = xbox(sg, xq);
                float4 bp3 = xbox(sp, xq);
                size_t ci = zb + (size_t)yo * 32 + xq;
                float4 cg = G[ci], cp = P[ci];
                float dgx = cg.x - bg3.x * inv, dgy = cg.y - bg3.y * inv;
                float dgz = cg.z - bg3.z * inv, dgw = cg.w - bg3.w * inv;
                float dpx = cp.x - bp3.x * inv, dpy = cp.y - bp3.y * inv;
                float dpz = cp.z - bp3.z * inv, dpw = cp.w - bp3.w * inv;
                a1 += dgx * dpx + dgy * dpy + dgz * dpz + dgw * dpw;
                a2 += dgx * dgx + dgy * dgy + dgz * dgz + dgw * dgw;
                a3 += dpx * dpx + dpy * dpy + dpz * dpz + dpw * dpw;
            }
        }
        block_reduce3_atomic((double)a1, (double)a2, (double)a3, dst);

    } else {
        // tversky: 1,048,576 float4 per pair, exactly 16/thread
        int id = b >> 1;                    // [0,512)
        int pair = id >> 8;
        int bid  = id & 255;
        const float4* Gp = (const float4*)(pair ? S1 : S0);
        const float4* Pp = (const float4*)(pair ? S1g : S0g);
        double* dst = ws + (pair ? 9 : 7);
        int idx = bid * 256 + tid;
        const int stride = 256 * 256;
        float asum = 0.f, aprod = 0.f;
        #pragma unroll
        for (int k = 0; k < 16; ++k) {
            int i = idx + k * stride;
            float4 xx = Gp[i], yy = Pp[i];
            asum  += (xx.x + yy.x) + (xx.y + yy.y) + (xx.z + yy.z) + (xx.w + yy.w);
            aprod += (xx.x * yy.x + xx.y * yy.y) + (xx.z * yy.z + xx.w * yy.w);
        }
        block_reduce2_atomic((double)asum, (double)aprod, dst);
    }
}

// ---------------- fallback (R4 mega, used if ws too small) ----------------

__global__ __launch_bounds__(256) void mega_fallback(
    const float* __restrict__ F0,  const float* __restrict__ F0g,
    const float* __restrict__ I0,  const float* __restrict__ I0R,
    const float* __restrict__ I1,  const float* __restrict__ I1R,
    const float* __restrict__ S0,  const float* __restrict__ S0g,
    const float* __restrict__ S1,  const float* __restrict__ S1g,
    double* __restrict__ ws)
{
    int b = blockIdx.x;
    int tid = threadIdx.x;
    int r = b & 3;

    if (r == 0) {
        __shared__ float4 xbuf[2][2][12][32];
        int lb = b >> 2;
        int q  = tid & 31;
        int rg = tid >> 5;
        int yt = lb & 15, zs = (lb >> 4) & 7;
        int batch = (lb >> 7) & 1, pair = lb >> 8;
        int y0 = yt << 3, z0 = zs << 4;

        const float* Vg = (pair ? I1  : I0)  + (size_t)batch * VOL;
        const float* Vp = (pair ? I1R : I0R) + (size_t)batch * VOL;
        double* dst = ws + (pair ? 4 : 1);

        int ry1 = y0 - 2 + rg;
        int ry2 = y0 + 6 + rg;
        bool ok1 = (ry1 >= 0);
        bool ok2 = (rg < 4) && (ry2 < 128);
        int ry1c = ok1 ? ry1 : 0;
        int ry2c = (ry2 < 128) ? ry2 : 0;

        float4 ringg[5], ringp[5];
        float a1 = 0.f, a2 = 0.f, a3 = 0.f;

        for (int o = 0; o < 4; ++o) {
            #pragma unroll
            for (int u = 0; u < 5; ++u) {
                int it = o * 5 + u;
                int z  = z0 - 2 + it;
                bool zok = (z >= 0) && (z < 128);
                int zc = zok ? z : 0;
                size_t zb = (size_t)zc * PLANE;
                int par = it & 1;

                float4 g1 = ((const float4*)(Vg + zb + (size_t)ry1c * 128))[q];
                float4 p1 = ((const float4*)(Vp + zb + (size_t)ry1c * 128))[q];
                float4 g2 = f4z(), p2 = f4z();
                if (rg < 4) {
                    g2 = ((const float4*)(Vg + zb + (size_t)ry2c * 128))[q];
                    p2 = ((const float4*)(Vp + zb + (size_t)ry2c * 128))[q];
                }
                float4 cg = f4z(), cp = f4z();
                if (it >= 4) {
                    size_t co = (size_t)(z - 2) * PLANE + (size_t)(y0 + rg) * 128;
                    cg = ((const float4*)(Vg + co))[q];
                    cp = ((const float4*)(Vp + co))[q];
                }
                bool v1 = zok && ok1, v2 = zok && ok2;
                if (!v1) { g1 = f4z(); p1 = f4z(); }
                if (!v2) { g2 = f4z(); p2 = f4z(); }

                xbuf[par][0][rg][q] = xbox(g1, q);
                xbuf[par][1][rg][q] = xbox(p1, q);
                if (rg < 4) {
                    xbuf[par][0][8 + rg][q] = xbox(g2, q);
                    xbuf[par][1][8 + rg][q] = xbox(p2, q);
                }
                __syncthreads();

                float4 yg = f4z(), yp = f4z();
                #pragma unroll
                for (int j = 0; j < 5; ++j) {
                    float4 tg = xbuf[par][0][rg + j][q];
                    float4 tp = xbuf[par][1][rg + j][q];
                    yg.x += tg.x; yg.y += tg.y; yg.z += tg.z; yg.w += tg.w;
                    yp.x += tp.x; yp.y += tp.y; yp.z += tp.z; yp.w += tp.w;
                }
                ringg[u] = yg;
                ringp[u] = yp;

                if (it >= 4) {
                    const float inv = 1.0f / 125.0f;
                    float4 mg, mp;
                    mg.x = (ringg[0].x+ringg[1].x+ringg[2].x+ringg[3].x+ringg[4].x)*inv;
                    mg.y = (ringg[0].y+ringg[1].y+ringg[2].y+ringg[3].y+ringg[4].y)*inv;
                    mg.z = (ringg[0].z+ringg[1].z+ringg[2].z+ringg[3].z+ringg[4].z)*inv;
                    mg.w = (ringg[0].w+ringg[1].w+ringg[2].w+ringg[3].w+ringg[4].w)*inv;
                    mp.x = (ringp[0].x+ringp[1].x+ringp[2].x+ringp[3].x+ringp[4].x)*inv;
                    mp.y = (ringp[0].y+ringp[1].y+ringp[2].y+ringp[3].y+ringp[4].y)*inv;
                    mp.z = (ringp[0].z+ringp[1].z+ringp[2].z+ringp[3].z+ringp[4].z)*inv;
                    mp.w = (ringp[0].w+ringp[1].w+ringp[2].w+ringp[3].w+ringp[4].w)*inv;
                    float dgx = cg.x - mg.x, dgy = cg.y - mg.y;
                    float dgz = cg.z - mg.z, dgw = cg.w - mg.w;
                    float dpx = cp.x - mp.x, dpy = cp.y - mp.y;
                    float dpz = cp.z - mp.z, dpw = cp.w - mp.w;
                    a1 += dgx*dpx + dgy*dpy + dgz*dpz + dgw*dpw;
                    a2 += dgx*dgx + dgy*dgy + dgz*dgz + dgw*dgw;
                    a3 += dpx*dpx + dpy*dpy + dpz*dpz + dpw*dpw;
                }
            }
        }
        block_reduce3_atomic((double)a1, (double)a2, (double)a3, dst);

    } else if (r != 3) {
        int bid = (b >> 2) * 2 + (r - 1);
        const float4* A = (const float4*)F0;
        const float4* B = (const float4*)F0g;
        int idx = bid * 256 + tid;
        const int stride = SQ_BLOCKS * 256;
        float acc = 0.f;
        #pragma unroll
        for (int k = 0; k < 12; ++k) {
            int i = idx + k * stride;
            float4 xx = A[i], yy = B[i];
            float d0 = yy.x - xx.x, d1 = yy.y - xx.y;
            float d2 = yy.z - xx.z, d3 = yy.w - xx.w;
            acc += (d0 * d0 + d1 * d1) + (d2 * d2 + d3 * d3);
        }
        block_reduce1_atomic((double)acc, &ws[0]);

    } else {
        int idx0 = b >> 2;
        int pair = idx0 >> 8;
        int bid  = idx0 & 255;
        const float4* Gp = (const float4*)(pair ? S1 : S0);
        const float4* Pp = (const float4*)(pair ? S1g : S0g);
        double* dst = ws + (pair ? 9 : 7);
        int idx = bid * 256 + tid;
        const int stride = 256 * 256;
        float asum = 0.f, aprod = 0.f;
        #pragma unroll
        for (int k = 0; k < 16; ++k) {
            int i = idx + k * stride;
            float4 xx = Gp[i], yy = Pp[i];
            asum  += (xx.x + yy.x) + (xx.y + yy.y) + (xx.z + yy.z) + (xx.w + yy.w);
            aprod += (xx.x * yy.x + xx.y * yy.y) + (xx.z * yy.z + xx.w * yy.w);
        }
        block_reduce2_atomic((double)asum, (double)aprod, dst);
    }
}

__global__ void finalize_kernel(const double* __restrict__ ws, float* out) {
    if (threadIdx.x == 0 && blockIdx.x == 0) {
        double reg = sqrt(ws[0]) / 12582912.0;

        double num0 = ws[1] * ws[1];
        double den0 = ws[2] * ws[3];
        if (den0 < 1e-5) den0 = 1e-5;
        double l0 = -(1.0 / 4194304.0) * (num0 / den0);

        double num1 = ws[4] * ws[4];
        double den1 = ws[5] * ws[6];
        if (den1 < 1e-5) den1 = 1e-5;
        double l1 = -(1.0 / 4194304.0) * (num1 / den1);

        double td0 = ws[7]; if (td0 < 1e-5) td0 = 1e-5;
        double t0 = -ws[8] / td0;
        double td1 = ws[9]; if (td1 < 1e-5) td1 = 1e-5;
        double t1 = -ws[10] / td1;

        out[0] = (float)(reg + 10.0 * (l0 + l1) + 10.0 * (t0 + t1));
    }
}

// ---------------- launch ----------------

extern "C" void kernel_launch(void* const* d_in, const int* in_sizes, int n_in,
                              void* d_out, int out_size, void* d_ws, size_t ws_size,
                              hipStream_t stream) {
    double* ws = (double*)d_ws;
    float* out = (float*)d_out;

    const float* F0  = (const float*)d_in[0];
    const float* F0g = (const float*)d_in[1];
    const float* I0  = (const float*)d_in[2];
    const float* I0R = (const float*)d_in[3];
    const float* I1  = (const float*)d_in[4];
    const float* I1R = (const float*)d_in[5];
    const float* S0  = (const float*)d_in[6];
    const float* S0g = (const float*)d_in[7];
    const float* S1  = (const float*)d_in[8];
    const float* S1g = (const float*)d_in[9];

    const size_t need = 256 + (size_t)8 * VOL * sizeof(float);   // ~67.1 MB

    zero_ws_kernel<<<1, 64, 0, stream>>>(ws);

    if (ws_size >= need) {
        float* bz = (float*)((char*)d_ws + 256);
        k_zpass_sq<<<1536, 256, 0, stream>>>(F0, F0g, I0, I0R, I1, I1R, ws, bz);
        k_lcc_tv<<<1024, 256, 0, stream>>>(I0, I0R, I1, I1R, S0, S0g, S1, S1g, ws, bz);
    } else {
        mega_fallback<<<2048, 256, 0, stream>>>(F0, F0g, I0, I0R, I1, I1R,
                                                S0, S0g, S1, S1g, ws);
    }

    finalize_kernel<<<1, 64, 0, stream>>>(ws, out);
}